// Round 5
// baseline (1206.511 us; speedup 1.0000x reference)
//
#include <hip/hip_runtime.h>
#include <cstdint>
#include <cstddef>

#define M_DIM 2048
#define N_DIM 4096
#define K_DIM 20000
#define NNZ_KCHUNK 256
#define NTILES 32                 /* n-tiles of 128 cols */
#define KCHUNKS 79                /* ceil(20000/256) */
#define NBUCK (NTILES * KCHUNKS)  /* 2528 */

#define XB_OFFSET   163840000UL   /* bf16 x after Wbt */
#define CP_OFFSET   245760000UL   /* 4x fp32 C-partials */
#define REC_OFFSET  312868864UL   /* 2M x 4B records */
#define CNT_OFFSET  320868864UL   /* counts  [2528] */
#define START_OFFSET 320878976UL  /* start   [2529] */
#define CUR_OFFSET  320889600UL   /* cursor  [2528] */

typedef __attribute__((ext_vector_type(8))) short short8;
typedef __attribute__((ext_vector_type(4))) float float4v;
typedef __attribute__((ext_vector_type(8))) unsigned short ushort8;

__device__ __forceinline__ unsigned short f2bf_rne(float f) {
    union { float f; unsigned int u; } v; v.f = f;
    unsigned int u = v.u;
    u += 0x7FFFu + ((u >> 16) & 1u);   // round-to-nearest-even
    return (unsigned short)(u >> 16);
}

__device__ __forceinline__ float bf2f(unsigned short h) {
    union { unsigned int u; float f; } v;
    v.u = ((unsigned int)h) << 16;
    return v.f;
}

__device__ __forceinline__ void gload_lds16(const void* g, void* l) {
    __builtin_amdgcn_global_load_lds(
        (const __attribute__((address_space(1))) void*)g,
        (__attribute__((address_space(3))) void*)l, 16, 0, 0);
}

// ---- 1a. histogram nnz per (n-tile, k-chunk) bucket ----
__global__ void hist_kernel(const int* __restrict__ ind,
                            unsigned int* __restrict__ counts, int nnz) {
    int t = blockIdx.x * blockDim.x + threadIdx.x;
    if (t >= nnz) return;
    int r = ind[2 * t];      // K index
    int c = ind[2 * t + 1];  // N index
    atomicAdd(&counts[(c >> 7) * KCHUNKS + (r >> 8)], 1u);
}

// ---- 1b. exclusive prefix scan over 2528 counts (single block, 512 thr) ----
__global__ __launch_bounds__(512) void scan_kernel(
    const unsigned int* __restrict__ counts,
    unsigned int* __restrict__ start,
    unsigned int* __restrict__ cursor) {
    __shared__ unsigned int part[512];
    const int t = threadIdx.x;
    const int base = t * 5;                 // 512*5 = 2560 >= 2528
    unsigned int local[5];
    unsigned int s = 0;
    #pragma unroll
    for (int i = 0; i < 5; ++i) {
        int b = base + i;
        local[i] = (b < NBUCK) ? counts[b] : 0u;
        s += local[i];
    }
    part[t] = s;
    __syncthreads();
    for (int off = 1; off < 512; off <<= 1) {
        unsigned int v = (t >= off) ? part[t - off] : 0u;
        __syncthreads();
        part[t] += v;
        __syncthreads();
    }
    unsigned int run = (t > 0) ? part[t - 1] : 0u;   // exclusive
    #pragma unroll
    for (int i = 0; i < 5; ++i) {
        int b = base + i;
        if (b < NBUCK) { start[b] = run; cursor[b] = run; run += local[i]; }
    }
    if (t == 511) start[NBUCK] = part[511];
}

// ---- 1c. scatter nnz into bucket-ordered 4-B records ----
// rec = (bf16(val) << 16) | (c_local<7b> << 8) | k_local<8b>
__global__ void recscat_kernel(const float* __restrict__ kv,
                               const int* __restrict__ ind,
                               unsigned int* __restrict__ cursor,
                               unsigned int* __restrict__ recs, int nnz) {
    int t = blockIdx.x * blockDim.x + threadIdx.x;
    if (t >= nnz) return;
    int r = ind[2 * t];
    int c = ind[2 * t + 1];
    unsigned int b = (unsigned)(c >> 7) * KCHUNKS + (unsigned)(r >> 8);
    unsigned int pos = atomicAdd(&cursor[b], 1u);
    unsigned int h = f2bf_rne(kv[t]);
    recs[pos] = (h << 16) | ((unsigned)(c & 127) << 8) | (unsigned)(r & 255);
}

// ---- 1d. densify: one block per bucket, LDS tile 128x256 bf16 (64 KB) ----
// Zero LDS, apply records via LDS-CAS (duplicate accumulation), stream out.
// Writes EVERY byte of W^T -> no global memset needed.
__global__ __launch_bounds__(512) void densify_kernel(
    const unsigned int* __restrict__ recs,
    const unsigned int* __restrict__ start,
    unsigned short* __restrict__ W) {
    __shared__ unsigned int tile[16384];    // 128 rows x 256 bf16 = 64 KB
    const int b = blockIdx.x;
    const int n = b / KCHUNKS;
    const int kc = b - n * KCHUNKS;
    const int t = threadIdx.x;

    uint4* t4 = (uint4*)tile;
    #pragma unroll
    for (int i = 0; i < 8; ++i)             // 4096 uint4 / 512 thr
        t4[t + 512 * i] = (uint4){0u, 0u, 0u, 0u};
    __syncthreads();

    const unsigned int s0 = start[b], s1 = start[b + 1];
    for (unsigned int i = s0 + t; i < s1; i += 512) {
        unsigned int rec = recs[i];
        unsigned int k  = rec & 255u;
        unsigned int cl = (rec >> 8) & 127u;
        unsigned short val = (unsigned short)(rec >> 16);
        unsigned int idx = cl * 256u + k;
        unsigned int word = idx >> 1;
        const bool hi = (idx & 1u) != 0;
        unsigned int old = tile[word], assumed;
        do {
            assumed = old;
            unsigned short cur = hi ? (unsigned short)(assumed >> 16)
                                    : (unsigned short)(assumed & 0xFFFFu);
            unsigned short nh = f2bf_rne(bf2f(cur) + bf2f(val));
            unsigned int nw = hi ? ((assumed & 0x0000FFFFu) | ((unsigned)nh << 16))
                                 : ((assumed & 0xFFFF0000u) | (unsigned)nh);
            old = atomicCAS(&tile[word], assumed, nw);
        } while (old != assumed);
    }
    __syncthreads();

    const int kbase = kc * NNZ_KCHUNK;
    if (kbase + NNZ_KCHUNK <= K_DIM) {
        // full chunk: 128 rows x 32 uint4/row = 4096 vec stores
        #pragma unroll
        for (int i = 0; i < 8; ++i) {
            int idx = t + 512 * i;
            int cl = idx >> 5, v = idx & 31;
            *(uint4*)(W + (size_t)(n * 128 + cl) * K_DIM + kbase + v * 8) =
                ((const uint4*)tile)[cl * 32 + v];
        }
    } else {
        // tail chunk (kc=78): only 32 k valid -> 128 rows x 4 uint4
        int cl = t >> 2, v = t & 3;        // 512 threads cover exactly 128x4
        *(uint4*)(W + (size_t)(n * 128 + cl) * K_DIM + kbase + v * 8) =
            ((const uint4*)tile)[cl * 32 + v];
    }
}

// ---- 2. streaming fp32 -> bf16 convert (for x), 8 elements per thread ----
__global__ void convert_kernel(const float* __restrict__ src,
                               unsigned short* __restrict__ dst) {
    size_t t = (size_t)blockIdx.x * 256 + threadIdx.x;
    const float4* sv = (const float4*)src;
    float4 a = sv[2 * t];
    float4 b = sv[2 * t + 1];
    ushort8 o;
    o[0] = f2bf_rne(a.x); o[1] = f2bf_rne(a.y);
    o[2] = f2bf_rne(a.z); o[3] = f2bf_rne(a.w);
    o[4] = f2bf_rne(b.x); o[5] = f2bf_rne(b.y);
    o[6] = f2bf_rne(b.z); o[7] = f2bf_rne(b.w);
    *(ushort8*)(dst + 8 * t) = o;
}

// ---- 3. split-K=4 GEMM partial (round-3 structure, swizzle reverted) ----
__global__ __launch_bounds__(256) void gemm_bt_partial_kernel(
    const unsigned short* __restrict__ A,
    const unsigned short* __restrict__ Bt,
    float* __restrict__ Cp) {

    __shared__ unsigned short Als[128 * 32];   // [m][k], row = 64 B
    __shared__ unsigned short Bls[128 * 32];   // [n][k]

    const int t    = threadIdx.x;
    const int wid  = t >> 6;
    const int lane = t & 63;
    const int quad = lane >> 4;
    const int r16  = lane & 15;
    const int wm   = wid >> 1;
    const int wn   = wid & 1;

    const int m0 = blockIdx.y * 128;
    const int n0 = blockIdx.x * 128;
    const int z  = blockIdx.z;
    const int iters = z ? 156 : 157;              // sum 625 = 20000/32
    const int k0 = (z ? (157 + 156 * (z - 1)) : 0) * 32;

    const unsigned short* gA0 = A  + (size_t)(m0 + (t >> 2)) * K_DIM + (t & 3) * 8 + k0;
    const unsigned short* gA1 = gA0 + (size_t)64 * K_DIM;
    const unsigned short* gB0 = Bt + (size_t)(n0 + (t >> 2)) * K_DIM + (t & 3) * 8 + k0;
    const unsigned short* gB1 = gB0 + (size_t)64 * K_DIM;

    char* lA0 = (char*)Als + wid * 1024;          // wave-uniform bases
    char* lA1 = (char*)Als + 4096 + wid * 1024;
    char* lB0 = (char*)Bls + wid * 1024;
    char* lB1 = (char*)Bls + 4096 + wid * 1024;

    const int abase = (wm * 64 + r16) * 64 + quad * 16;
    const int bbase = (wn * 64 + r16) * 64 + quad * 16;

    float4v acc[4][4];
    #pragma unroll
    for (int i = 0; i < 4; ++i)
        #pragma unroll
        for (int j = 0; j < 4; ++j)
            acc[i][j] = (float4v){0.f, 0.f, 0.f, 0.f};

    for (int kt = 0; kt < iters; ++kt) {
        gload_lds16(gA0, lA0);
        gload_lds16(gA1, lA1);
        gload_lds16(gB0, lB0);
        gload_lds16(gB1, lB1);
        gA0 += 32; gA1 += 32; gB0 += 32; gB1 += 32;
        __syncthreads();

        short8 af[4], bfr[4];
        #pragma unroll
        for (int i = 0; i < 4; ++i)
            af[i] = *(const short8*)((const char*)Als + abase + i * 1024);
        #pragma unroll
        for (int j = 0; j < 4; ++j)
            bfr[j] = *(const short8*)((const char*)Bls + bbase + j * 1024);

        #pragma unroll
        for (int i = 0; i < 4; ++i)
            #pragma unroll
            for (int j = 0; j < 4; ++j)
                acc[i][j] = __builtin_amdgcn_mfma_f32_16x16x32_bf16(
                    af[i], bfr[j], acc[i][j], 0, 0, 0);
        __syncthreads();
    }

    float* Cz = Cp + (size_t)z * M_DIM * N_DIM;
    #pragma unroll
    for (int i = 0; i < 4; ++i) {
        const int row = m0 + wm * 64 + i * 16 + quad * 4;
        #pragma unroll
        for (int j = 0; j < 4; ++j) {
            const int col = n0 + wn * 64 + j * 16 + r16;
            #pragma unroll
            for (int r = 0; r < 4; ++r)
                Cz[(size_t)(row + r) * N_DIM + col] = acc[i][j][r];
        }
    }
}

// ---- 4. combine: out = tanh(C0 + C1 + C2 + C3 + bias) ----
__global__ void combine_kernel(const float* __restrict__ Cp,
                               const float* __restrict__ bias,
                               float* __restrict__ out) {
    size_t t = (size_t)blockIdx.x * 256 + threadIdx.x;       // per float4
    const size_t stride = (size_t)M_DIM * N_DIM / 4;
    float4 a = ((const float4*)Cp)[t];
    float4 b = ((const float4*)Cp)[t + stride];
    float4 c = ((const float4*)Cp)[t + 2 * stride];
    float4 d = ((const float4*)Cp)[t + 3 * stride];
    float4 bv = ((const float4*)bias)[t & (N_DIM / 4 - 1)];
    float4 o;
    o.x = tanhf(a.x + b.x + c.x + d.x + bv.x);
    o.y = tanhf(a.y + b.y + c.y + d.y + bv.y);
    o.z = tanhf(a.z + b.z + c.z + d.z + bv.z);
    o.w = tanhf(a.w + b.w + c.w + d.w + bv.w);
    ((float4*)out)[t] = o;
}

extern "C" void kernel_launch(void* const* d_in, const int* in_sizes, int n_in,
                              void* d_out, int out_size, void* d_ws, size_t ws_size,
                              hipStream_t stream) {
    const float* x    = (const float*)d_in[0];
    const float* kv   = (const float*)d_in[1];
    const float* bias = (const float*)d_in[2];
    const int*   ind  = (const int*)d_in[3];
    const int nnz = in_sizes[1];

    unsigned short* Wbt   = (unsigned short*)d_ws;                        // 163.84 MB
    unsigned short* xb    = (unsigned short*)((char*)d_ws + XB_OFFSET);   // 81.92 MB
    float*          Cp    = (float*)((char*)d_ws + CP_OFFSET);            // 67.1 MB
    unsigned int*   recs  = (unsigned int*)((char*)d_ws + REC_OFFSET);    // 8 MB
    unsigned int*   cnts  = (unsigned int*)((char*)d_ws + CNT_OFFSET);
    unsigned int*   start = (unsigned int*)((char*)d_ws + START_OFFSET);
    unsigned int*   cur   = (unsigned int*)((char*)d_ws + CUR_OFFSET);

    // 1. bucketed W^T build (no 164 MB memset, no HBM atomics)
    hipMemsetAsync(cnts, 0, NBUCK * sizeof(unsigned int), stream);
    hist_kernel<<<(nnz + 255) / 256, 256, 0, stream>>>(ind, cnts, nnz);
    scan_kernel<<<1, 512, 0, stream>>>(cnts, start, cur);
    recscat_kernel<<<(nnz + 255) / 256, 256, 0, stream>>>(kv, ind, cur, recs, nnz);
    densify_kernel<<<NBUCK, 512, 0, stream>>>(recs, start, Wbt);
    // 2. x fp32 -> bf16
    convert_kernel<<<(M_DIM * K_DIM) / (256 * 8), 256, 0, stream>>>(x, xb);
    // 3. split-K=4 GEMM partials (3D grid, no swizzle)
    gemm_bt_partial_kernel<<<dim3(N_DIM / 128, M_DIM / 128, 4), 256, 0, stream>>>(
        xb, Wbt, Cp);
    // 4. combine + bias + tanh
    combine_kernel<<<(M_DIM * N_DIM) / (256 * 4), 256, 0, stream>>>(
        Cp, bias, (float*)d_out);
}